// Round 1
// 534.677 us; speedup vs baseline: 1.0409x; 1.0409x over previous
//
#include <hip/hip_runtime.h>
#include <hip/hip_bf16.h>
#include <stdint.h>

typedef __bf16 bf16;
typedef __attribute__((ext_vector_type(8))) __bf16 bf16x8;
typedef __attribute__((ext_vector_type(4))) float f32x4;

#define NNODE 20000
#define NEDGE 160000
#define NFEATD 512
#define NHIDD 256
#define NCLSD 64

// async global->LDS, 16B per lane (wave-uniform base + lane*16 contiguous)
__device__ __forceinline__ void async_copy16(const bf16* g, bf16* l) {
  __builtin_amdgcn_global_load_lds((__attribute__((address_space(1))) void*)g,
                                   (__attribute__((address_space(3))) void*)l,
                                   16, 0, 0);
}

// ---------------------------------------------------------------------------
// GEMM: Cint[M x Nint] = [A1|A2] @ [W1|W2]^T, fp32 accum.
// K-loop: BK=64, double-buffered LDS, depth-2 prefetch with counted
// s_waitcnt vmcnt(8) (never drained in main loop), raw s_barrier,
// XOR-swizzled LDS (slot ^= row&7) via pre-swizzled global_load_lds SOURCE
// addresses (LDS dest stays linear), setprio(1) around MFMA cluster,
// bijective XCD-chunked block swizzle for A-panel L2 reuse.
// MODE 0: outB[r*ldC+c] = bf16(Cint)
// MODE 2: interleaved gamma/beta FiLM epilogue -> outG fp32 + outB2 bf16
// MODE 3: hk = (agg + dinv^2*hself + bias + C)*rnb, opt elu -> outB bf16
// MODE 4: MODE3 (no elu) + fused log_softmax over 64 cols -> outF, outF2
// ---------------------------------------------------------------------------
struct GemmArgs {
  const bf16 *A1, *A2, *W1, *W2, *zpage;
  int ldA, ldW, K1, Ktot, Nvalid, ldC, Nrows, Arows, Wrows;
  bf16* outB;
  float* outF;
  float* outF2;
  const float* mrow;   // MODE 2
  const float* Xf;     // MODE 2 layer1 ft fp32 (or null)
  const bf16* Xh;      // MODE 2 layer2 ft bf16
  const bf16* nbm;     // MODE 2
  float* outG;         // MODE 2 fp32 into d_out
  bf16* outB2;         // MODE 2 bf16 copy
  const float* agg;    // MODE 3/4
  const bf16* hself;
  int hld;
  const float* dinv;
  const float* bias;
  const float* rnb;
  int elu;
};

template <int MODE>
__global__ __launch_bounds__(256) void gemm_bt(GemmArgs ga) {
  __shared__ bf16 sA[2][128 * 64];
  __shared__ bf16 sB[2][128 * 64];
  const int tid = threadIdx.x;
  const int lane = tid & 63;
  const int w = tid >> 6;
  const int wm = w >> 1, wn = w & 1;

  // --- bijective XCD-chunked block swizzle (m204): hw XCD = linear%8 gets a
  // contiguous chunk of tiles -> A row-panels reused across column blocks in L2.
  const int gx = gridDim.x;
  const int nwg = gx * gridDim.y;
  const int orig = blockIdx.y * gx + blockIdx.x;
  const int qq = nwg >> 3, rm = nwg & 7;
  const int xcd = orig & 7, sidx = orig >> 3;
  const int wg = (xcd < rm ? xcd * (qq + 1) : rm * (qq + 1) + (xcd - rm) * qq) + sidx;
  const int bn0 = (wg % gx) * 128;
  const int bm0 = (wg / gx) * 128;

  // --- staging precompute. Thread writes LDS rows r*32+(tid>>3), phys 16B-slot
  // tid&7. Swizzled layout: LDS(row, s) holds logical slot s^(row&7), so the
  // SOURCE fetches logical slot (tid&7)^((tid>>3)&7)  (involution, round-invariant).
  const int srow = tid >> 3;
  const int scol = (((tid & 7) ^ (srow & 7)) << 3);  // element offset within row
  const bf16* zp = ga.zpage + tid * 8;
  int offA[4], offB[4];
  bool okA[4], okB[4];
#pragma unroll
  for (int r = 0; r < 4; r++) {
    const int ra = bm0 + r * 32 + srow;
    const int rb = bn0 + r * 32 + srow;
    okA[r] = ra < ga.Arows;
    okB[r] = rb < ga.Wrows;
    offA[r] = ra * ga.ldA + scol;
    offB[r] = rb * ga.ldW + scol;
  }
  const int nt1 = ga.K1 >> 6;
  const int nt = ga.Ktot >> 6;

  auto stage = [&](int t, int p) {
    const int seg = t >= nt1;
    const int koff = (t - (seg ? nt1 : 0)) << 6;
    const bf16* As = seg ? ga.A2 : ga.A1;
    const bf16* Ws = seg ? ga.W2 : ga.W1;
    bf16* dA = &sA[p][tid * 8];
    bf16* dB = &sB[p][tid * 8];
#pragma unroll
    for (int r = 0; r < 4; r++)
      async_copy16(okA[r] ? As + offA[r] + koff : zp, dA + r * 2048);
#pragma unroll
    for (int r = 0; r < 4; r++)
      async_copy16(okB[r] ? Ws + offB[r] + koff : zp, dB + r * 2048);
  };

  // --- fragment-read precompute (bytes within one buffer).
  // A-frag(mi,kk): row = wm*64+mi*16+(lane&15), logical slot kk*4+(lane>>4),
  // phys slot = logical ^ (row&7); row&7 is mi-invariant (16 = 0 mod 8).
  const int sl = lane >> 4;
  const int rAb = wm * 64 + (lane & 15);
  const int rBb = wn * 64 + (lane & 15);
  const int a7 = rAb & 7, b7 = rBb & 7;

  f32x4 acc[4][4] = {};

  // --- prologue: stage tiles 0,1; wait tile0 (8 of tile1 stay in flight).
  stage(0, 0);
  stage(1, 1);
  asm volatile("s_waitcnt vmcnt(8)" ::: "memory");
  __builtin_amdgcn_s_barrier();
  asm volatile("" ::: "memory");

  for (int t = 0; t < nt; ++t) {
    const int p = t & 1;
    const bf16* pA = &sA[p][0];
    const bf16* pB = &sB[p][0];
    bf16x8 af[4][2], bv[4][2];
#pragma unroll
    for (int mi = 0; mi < 4; mi++)
#pragma unroll
      for (int kk = 0; kk < 2; kk++)
        af[mi][kk] = *(const bf16x8*)((const char*)pA + (rAb + mi * 16) * 128 +
                                      ((((kk << 2) + sl) ^ a7) << 4));
#pragma unroll
    for (int ni = 0; ni < 4; ni++)
#pragma unroll
      for (int kk = 0; kk < 2; kk++)
        bv[ni][kk] = *(const bf16x8*)((const char*)pB + (rBb + ni * 16) * 128 +
                                      ((((kk << 2) + sl) ^ b7) << 4));
    if (t + 2 < nt) {
      // release buf p for overwrite: my reads complete, then block-wide join.
      asm volatile("s_waitcnt lgkmcnt(0)" ::: "memory");
      __builtin_amdgcn_s_barrier();
      asm volatile("" ::: "memory");
      stage(t + 2, p);  // issue early: HBM latency hides under MFMA below
    }
    __builtin_amdgcn_s_setprio(1);
#pragma unroll
    for (int mi = 0; mi < 4; mi++)
#pragma unroll
      for (int ni = 0; ni < 4; ni++)
#pragma unroll
        for (int kk = 0; kk < 2; kk++)
          acc[mi][ni] =
              __builtin_amdgcn_mfma_f32_16x16x32_bf16(af[mi][kk], bv[ni][kk], acc[mi][ni], 0, 0, 0);
    __builtin_amdgcn_s_setprio(0);
    if (t + 1 < nt) {
      // tile t+1 must be resident before next group's ds_reads. Counted wait:
      // outstanding = 8 (t+1) + 8 (t+2 just issued) -> vmcnt(8) waits t+1 only.
      if (t + 2 < nt) asm volatile("s_waitcnt vmcnt(8)" ::: "memory");
      else            asm volatile("s_waitcnt vmcnt(0)" ::: "memory");
      __builtin_amdgcn_s_barrier();
      asm volatile("" ::: "memory");
    }
  }

  if constexpr (MODE == 0) {
    const int Nv = ga.Nvalid;
#pragma unroll
    for (int mi = 0; mi < 4; mi++) {
      const int rb = bm0 + wm * 64 + mi * 16 + ((lane >> 4) << 2);
#pragma unroll
      for (int ni = 0; ni < 4; ni++) {
        const int c = bn0 + wn * 64 + ni * 16 + (lane & 15);
#pragma unroll
        for (int i = 0; i < 4; i++) {
          const int r = rb + i;
          if (r < ga.Nrows && c < Nv) ga.outB[(size_t)r * ga.ldC + c] = (bf16)acc[mi][ni][i];
        }
      }
    }
  } else if constexpr (MODE == 2) {
    const int Dr = ga.Nvalid;  // logical width
    const int Lb = ((bn0 + wn * 64) >> 1) + (lane & 15);
#pragma unroll
    for (int mi = 0; mi < 4; mi++) {
      const int rb = bm0 + wm * 64 + mi * 16 + ((lane >> 4) << 2);
#pragma unroll
      for (int p = 0; p < 2; p++) {
        const int L = Lb + p * 16;
        const float mv = ga.mrow[L];
#pragma unroll
        for (int i = 0; i < 4; i++) {
          const int r = rb + i;
          if (r >= ga.Nrows) continue;
          const size_t idx = (size_t)r * Dr + L;
          float vg = acc[mi][2 * p][i];
          float vb = acc[mi][2 * p + 1][i];
          float gamma = (vg > 0.f ? vg : 0.2f * vg) + 1.0f;
          float beta = vb > 0.f ? vb : 0.2f * vb;
          float ft = ga.Xf ? ga.Xf[idx] : (float)ga.Xh[idx];
          float o = ft + gamma * mv + beta - (float)ga.nbm[idx];
          ga.outG[idx] = o;
          ga.outB2[idx] = (bf16)o;
        }
      }
    }
  } else if constexpr (MODE == 3) {
    const int Nv = ga.Nvalid;
#pragma unroll
    for (int mi = 0; mi < 4; mi++) {
      const int rb = bm0 + wm * 64 + mi * 16 + ((lane >> 4) << 2);
#pragma unroll
      for (int ni = 0; ni < 4; ni++) {
        const int c = bn0 + wn * 64 + ni * 16 + (lane & 15);
#pragma unroll
        for (int i = 0; i < 4; i++) {
          const int r = rb + i;
          if (r >= ga.Nrows || c >= Nv) continue;
          const size_t idx = (size_t)r * ga.ldC + c;
          float dv = ga.dinv[r];
          float hs = (float)ga.hself[(size_t)r * ga.hld + c];
          float hv = (ga.agg[idx] + dv * dv * hs + ga.bias[c] + acc[mi][ni][i]) * ga.rnb[r];
          if (ga.elu) hv = hv > 0.f ? hv : expm1f(hv);
          ga.outB[idx] = (bf16)hv;
        }
      }
    }
  } else {  // MODE 4: GCN combine + fused log_softmax (Nvalid == 64, wn==0 waves only)
    if (wn == 0) {
#pragma unroll
      for (int mi = 0; mi < 4; mi++) {
        const int rb = bm0 + wm * 64 + mi * 16 + ((lane >> 4) << 2);
#pragma unroll
        for (int i = 0; i < 4; i++) {
          const int r = rb + i;
          const bool ok = r < ga.Nrows;  // uniform within the 16-lane shuffle group
          float dv = ok ? ga.dinv[r] : 0.f;
          float rn = ok ? ga.rnb[r] : 1.f;
          float hv[4];
#pragma unroll
          for (int ni = 0; ni < 4; ni++) {
            const int c = ni * 16 + (lane & 15);
            float hs = ok ? (float)ga.hself[(size_t)r * ga.hld + c] : 0.f;
            float ag = ok ? ga.agg[(size_t)r * 64 + c] : 0.f;
            hv[ni] = ok ? (ag + dv * dv * hs + ga.bias[c] + acc[mi][ni][i]) * rn : 0.f;
          }
          float mx = fmaxf(fmaxf(hv[0], hv[1]), fmaxf(hv[2], hv[3]));
          mx = fmaxf(mx, __shfl_xor(mx, 1));
          mx = fmaxf(mx, __shfl_xor(mx, 2));
          mx = fmaxf(mx, __shfl_xor(mx, 4));
          mx = fmaxf(mx, __shfl_xor(mx, 8));
          float s = expf(hv[0] - mx) + expf(hv[1] - mx) + expf(hv[2] - mx) + expf(hv[3] - mx);
          s += __shfl_xor(s, 1);
          s += __shfl_xor(s, 2);
          s += __shfl_xor(s, 4);
          s += __shfl_xor(s, 8);
          float ls = logf(s);
          if (ok) {
#pragma unroll
            for (int ni = 0; ni < 4; ni++) {
              const int c = ni * 16 + (lane & 15);
              ga.outF[(size_t)r * 64 + c] = hv[ni];
              ga.outF2[(size_t)r * 64 + c] = hv[ni] - mx - ls;
            }
          }
        }
      }
    }
  }
}

// ---------------------------------------------------------------------------
__global__ void cvt_f2b(const float* __restrict__ src, bf16* __restrict__ dst, int n) {
  int i = (blockIdx.x * 256 + threadIdx.x) * 4;
  if (i >= n) return;
  float4 v = *(const float4*)(src + i);
  dst[i + 0] = (bf16)v.x;
  dst[i + 1] = (bf16)v.y;
  dst[i + 2] = (bf16)v.z;
  dst[i + 3] = (bf16)v.w;
}

// Interleaved relation-weight builder: dst[2D][2D] bf16.
// Row R: q=R>>5, s=R&31, src row = q*16 + (s&15); gamma if s<16 else beta.
// Col C: first K-half (C<D) from *1, second from *2.
__global__ void build_rel_w(const float* __restrict__ g1, const float* __restrict__ g2,
                            const float* __restrict__ b1, const float* __restrict__ b2,
                            bf16* __restrict__ dst, int D) {
  int idx = (blockIdx.x * 256 + threadIdx.x) * 4;
  if (idx >= 4 * D * D) return;
  int R = idx / (2 * D), C = idx % (2 * D);
  int q = R >> 5, s = R & 31;
  int sr = q * 16 + (s & 15);
  const float* src = (s < 16) ? ((C < D) ? g1 : g2) : ((C < D) ? b1 : b2);
  int cc = (C < D) ? C : C - D;
  float4 v = *(const float4*)(src + (size_t)sr * D + cc);
  union { bf16 b[4]; uint2 u; } o;
  o.b[0] = (bf16)v.x; o.b[1] = (bf16)v.y; o.b[2] = (bf16)v.z; o.b[3] = (bf16)v.w;
  *(uint2*)(dst + (size_t)R * 2 * D + C) = o.u;
}

// ---------------------------------------------------------------------------
// CSR build
// ---------------------------------------------------------------------------
__global__ void count_int(const int* __restrict__ ei, int* cr, int* cc, int E) {
  int e = blockIdx.x * 256 + threadIdx.x;
  if (e < E) {
    atomicAdd(&cr[ei[e]], 1);
    atomicAdd(&cc[ei[E + e]], 1);
  }
}

__global__ void scan_excl2(const int* __restrict__ cr, const int* __restrict__ cc,
                           int* __restrict__ rptr, int* __restrict__ cptr,
                           int* __restrict__ curr, int* __restrict__ curc, int n) {
  const int* cnt = blockIdx.x ? cc : cr;
  int* ptr = blockIdx.x ? cptr : rptr;
  int* cur = blockIdx.x ? curc : curr;
  __shared__ int part[256];
  int t = threadIdx.x;
  int chunk = (n + 255) / 256;
  int base = t * chunk;
  int s = 0;
  for (int i = 0; i < chunk; i++) {
    int j = base + i;
    if (j < n) s += cnt[j];
  }
  part[t] = s;
  __syncthreads();
  if (t == 0) {
    int r = 0;
    for (int i = 0; i < 256; i++) { int v = part[i]; part[i] = r; r += v; }
    ptr[n] = r;
  }
  __syncthreads();
  int run = part[t];
  for (int i = 0; i < chunk; i++) {
    int j = base + i;
    if (j < n) {
      ptr[j] = run;
      cur[j] = run;
      run += cnt[j];
    }
  }
}

__global__ void csr_fill(const int* __restrict__ ei, int* cur_r, int* cur_c,
                         int* __restrict__ adj_r, int* __restrict__ adj_c, int E) {
  int e = blockIdx.x * 256 + threadIdx.x;
  if (e >= E) return;
  int row = ei[e], col = ei[E + e];
  int p = atomicAdd(&cur_r[row], 1);
  adj_r[p] = col;
  int q = atomicAdd(&cur_c[col], 1);
  adj_c[q] = row;
}

__global__ void finalize_counts_i(const int* __restrict__ cr, const int* __restrict__ cc,
                                  float* nbscale, float* rnb, float* dinv, int n) {
  int i = blockIdx.x * 256 + threadIdx.x;
  if (i < n) {
    float a = (float)cr[i];
    nbscale[i] = 1.0f / fmaxf(a, 1.0f);
    rnb[i] = 1.0f / (a + 1.0f);
    dinv[i] = rsqrtf((float)cc[i] + 1.0f);
  }
}

// ---------------------------------------------------------------------------
// Gather SpMM (no atomics): one 64-lane wave per destination node.
// ---------------------------------------------------------------------------
__global__ void spmm_nb1(const int* __restrict__ rowptr, const int* __restrict__ adj,
                         const bf16* __restrict__ x, const float* __restrict__ nbscale,
                         bf16* __restrict__ nbp, int n) {
  int r = blockIdx.x * 4 + (threadIdx.x >> 6);
  if (r >= n) return;
  int lane = threadIdx.x & 63;
  int e0 = rowptr[r], e1 = rowptr[r + 1];
  float a[8] = {0.f, 0.f, 0.f, 0.f, 0.f, 0.f, 0.f, 0.f};
  for (int e = e0; e < e1; e++) {
    union { uint4 u; bf16 b[8]; } v;
    v.u = *(const uint4*)(x + (size_t)adj[e] * NFEATD + lane * 8);
#pragma unroll
    for (int j = 0; j < 8; j++) a[j] += (float)v.b[j];
  }
  float s = nbscale[r];
  union { bf16 b[8]; uint4 u; } o;
#pragma unroll
  for (int j = 0; j < 8; j++) o.b[j] = (bf16)(a[j] * s);
  *(uint4*)(nbp + (size_t)r * NFEATD + lane * 8) = o.u;
}

__global__ void spmm_nb2(const int* __restrict__ rowptr, const int* __restrict__ adj,
                         const bf16* __restrict__ x, const float* __restrict__ nbscale,
                         bf16* __restrict__ nbp, int n) {
  int r = blockIdx.x * 4 + (threadIdx.x >> 6);
  if (r >= n) return;
  int lane = threadIdx.x & 63;
  int e0 = rowptr[r], e1 = rowptr[r + 1];
  float a[4] = {0.f, 0.f, 0.f, 0.f};
  for (int e = e0; e < e1; e++) {
    union { uint2 u; bf16 b[4]; } v;
    v.u = *(const uint2*)(x + (size_t)adj[e] * NHIDD + lane * 4);
#pragma unroll
    for (int j = 0; j < 4; j++) a[j] += (float)v.b[j];
  }
  float s = nbscale[r];
  union { bf16 b[4]; uint2 u; } o;
#pragma unroll
  for (int j = 0; j < 4; j++) o.b[j] = (bf16)(a[j] * s);
  *(uint2*)(nbp + (size_t)r * NHIDD + lane * 4) = o.u;
}

__global__ void spmm_gcn256(const int* __restrict__ colptr, const int* __restrict__ adj,
                            const bf16* __restrict__ h, int hld, const float* __restrict__ dinv,
                            float* __restrict__ agg, int n) {
  int c = blockIdx.x * 4 + (threadIdx.x >> 6);
  if (c >= n) return;
  int lane = threadIdx.x & 63;
  int e0 = colptr[c], e1 = colptr[c + 1];
  float a[4] = {0.f, 0.f, 0.f, 0.f};
  for (int e = e0; e < e1; e++) {
    int rr = adj[e];
    float wv = dinv[rr];
    union { uint2 u; bf16 b[4]; } v;
    v.u = *(const uint2*)(h + (size_t)rr * hld + lane * 4);
#pragma unroll
    for (int j = 0; j < 4; j++) a[j] += wv * (float)v.b[j];
  }
  float wc = dinv[c];
  f32x4 o;
#pragma unroll
  for (int j = 0; j < 4; j++) o[j] = a[j] * wc;
  *(f32x4*)(agg + (size_t)c * NHIDD + lane * 4) = o;
}

__global__ void spmm_gcn64(const int* __restrict__ colptr, const int* __restrict__ adj,
                           const bf16* __restrict__ h, int hld, const float* __restrict__ dinv,
                           float* __restrict__ agg, int n) {
  int c = blockIdx.x * 4 + (threadIdx.x >> 6);
  if (c >= n) return;
  int lane = threadIdx.x & 63;
  int e0 = colptr[c], e1 = colptr[c + 1];
  float a = 0.f;
  for (int e = e0; e < e1; e++) {
    int rr = adj[e];
    a += dinv[rr] * (float)h[(size_t)rr * hld + lane];
  }
  agg[(size_t)c * NCLSD + lane] = a * dinv[c];
}

// ---------------------------------------------------------------------------
extern "C" void kernel_launch(void* const* d_in, const int* in_sizes, int n_in, void* d_out,
                              int out_size, void* d_ws, size_t ws_size, hipStream_t stream) {
  const float* x = (const float*)d_in[0];
  const int* ei = (const int*)d_in[1];
  // d_in[2] = head (always 0 -> tail branch)
  const float* r1g1 = (const float*)d_in[3];
  const float* r1g2 = (const float*)d_in[4];
  const float* r1b1 = (const float*)d_in[5];
  const float* r1b2 = (const float*)d_in[6];
  const float* r1m = (const float*)d_in[7];
  const float* gc1w = (const float*)d_in[8];
  const float* gc1b = (const float*)d_in[9];
  const float* r2g1 = (const float*)d_in[10];
  const float* r2g2 = (const float*)d_in[11];
  const float* r2b1 = (const float*)d_in[12];
  const float* r2b2 = (const float*)d_in[13];
  const float* r2m = (const float*)d_in[14];
  const float* gc2w = (const float*)d_in[15];
  const float* gc2b = (const float*)d_in[16];
  float* out = (float*)d_out;

  char* ws = (char*)d_ws;
  size_t off = 0;
  auto alloc = [&](size_t bytes) -> char* {
    char* p = ws + off;
    off = (off + bytes + 511) & ~(size_t)511;
    return p;
  };
  float* nbscale = (float*)alloc((size_t)NNODE * 4);
  float* rnb = (float*)alloc((size_t)NNODE * 4);
  float* dinv = (float*)alloc((size_t)NNODE * 4);
  int* icr = (int*)alloc((size_t)NNODE * 4);
  int* icc = (int*)alloc((size_t)NNODE * 4);
  int* rptr = (int*)alloc((size_t)(NNODE + 1) * 4);
  int* cptr = (int*)alloc((size_t)(NNODE + 1) * 4);
  int* curr = (int*)alloc((size_t)NNODE * 4);
  int* curc = (int*)alloc((size_t)NNODE * 4);
  int* adjr = (int*)alloc((size_t)NEDGE * 4);
  int* adjc = (int*)alloc((size_t)NEDGE * 4);
  bf16* zpage = (bf16*)alloc(8192);
  bf16* Wrel1 = (bf16*)alloc((size_t)1024 * 1024 * 2);  // interleaved [g;b] layer1
  bf16* Wrel2 = (bf16*)alloc((size_t)512 * 512 * 2);    // interleaved [g;b] layer2
  bf16* wgc1 = (bf16*)alloc((size_t)NHIDD * NFEATD * 2);
  bf16* wgc2 = (bf16*)alloc((size_t)NCLSD * NHIDD * 2);
  bf16* xb = (bf16*)alloc((size_t)NNODE * NFEATD * 2);     // 20.5 MB
  bf16* nbp1 = (bf16*)alloc((size_t)NNODE * NFEATD * 2);   // 20.5 MB
  bf16* out1b = (bf16*)alloc((size_t)NNODE * NFEATD * 2);  // 20.5 MB
  bf16* h1b = (bf16*)alloc((size_t)NNODE * NHIDD * 2);     // 10.2 MB
  float* agg1 = (float*)alloc((size_t)NNODE * NHIDD * 4);  // 20.5 MB
  bf16* x1b = (bf16*)alloc((size_t)NNODE * NHIDD * 2);     // 10.2 MB
  bf16* nb2p = (bf16*)alloc((size_t)NNODE * NHIDD * 2);    // 10.2 MB
  bf16* out2b = (bf16*)alloc((size_t)NNODE * NHIDD * 2);   // 10.2 MB
  bf16* h2b = (bf16*)alloc((size_t)NNODE * NCLSD * 2);     // 2.6 MB
  float* agg2 = (float*)alloc((size_t)NNODE * NCLSD * 4);  // 5.1 MB

  const size_t OUT1OFF = (size_t)2 * NNODE * NCLSD;
  const size_t OUT2OFF = OUT1OFF + (size_t)NNODE * NFEATD;
  float* out1g = out + OUT1OFF;
  float* out2g = out + OUT2OFF;

  const int MB = (NNODE + 127) / 128;  // 157
  const int NW4 = (NNODE + 3) / 4;

  // ---- CSR build + graph stats ----
  hipMemsetAsync(icr, 0, (size_t)NNODE * 4, stream);
  hipMemsetAsync(icc, 0, (size_t)NNODE * 4, stream);
  hipMemsetAsync(zpage, 0, 8192, stream);
  count_int<<<(NEDGE + 255) / 256, 256, 0, stream>>>(ei, icr, icc, NEDGE);
  scan_excl2<<<2, 256, 0, stream>>>(icr, icc, rptr, cptr, curr, curc, NNODE);
  finalize_counts_i<<<(NNODE + 255) / 256, 256, 0, stream>>>(icr, icc, nbscale, rnb, dinv, NNODE);
  csr_fill<<<(NEDGE + 255) / 256, 256, 0, stream>>>(ei, curr, curc, adjr, adjc, NEDGE);

  // ---- bf16 conversions ----
  cvt_f2b<<<(NNODE * NFEATD / 4 + 255) / 256, 256, 0, stream>>>(x, xb, NNODE * NFEATD);
  cvt_f2b<<<(NHIDD * NFEATD / 4 + 255) / 256, 256, 0, stream>>>(gc1w, wgc1, NHIDD * NFEATD);
  cvt_f2b<<<(NCLSD * NHIDD / 4 + 255) / 256, 256, 0, stream>>>(gc2w, wgc2, NCLSD * NHIDD);
  build_rel_w<<<(4 * 512 * 512 / 4 + 255) / 256, 256, 0, stream>>>(r1g1, r1g2, r1b1, r1b2, Wrel1, 512);
  build_rel_w<<<(4 * 256 * 256 / 4 + 255) / 256, 256, 0, stream>>>(r2g1, r2g2, r2b1, r2b2, Wrel2, 256);

  // ---- layer 1 neighbor mean ----
  spmm_nb1<<<NW4, 256, 0, stream>>>(rptr, adjr, xb, nbscale, nbp1, NNODE);

  GemmArgs a;
  auto base = [&](const bf16* A1, const bf16* A2, int ldA, const bf16* W1, const bf16* W2,
                  int ldW, int K1, int Kt, int Nv, int ldC, int Wr) {
    a = GemmArgs{};
    a.A1 = A1; a.A2 = A2; a.W1 = W1; a.W2 = W2; a.zpage = zpage;
    a.ldA = ldA; a.ldW = ldW; a.K1 = K1; a.Ktot = Kt; a.Nvalid = Nv; a.ldC = ldC;
    a.Nrows = NNODE; a.Arows = NNODE; a.Wrows = Wr;
  };

  // ---- layer-1 relation GEMM (interleaved gamma/beta, fused epilogue) ----
  base(xb, nbp1, NFEATD, Wrel1, Wrel1 + 512, 1024, NFEATD, 2 * NFEATD, NFEATD, NFEATD, 1024);
  a.mrow = r1m; a.Xf = x; a.nbm = nbp1; a.outG = out1g; a.outB2 = out1b;
  gemm_bt<2><<<dim3(8, MB), 256, 0, stream>>>(a);

  // ---- h1 = bf16(x @ gc1^T) ----
  base(xb, xb, NFEATD, wgc1, wgc1, NFEATD, NFEATD, NFEATD, NHIDD, NHIDD, NHIDD);
  a.outB = h1b;
  gemm_bt<0><<<dim3(2, MB), 256, 0, stream>>>(a);

  // ---- GCN aggregation layer 1 ----
  spmm_gcn256<<<NW4, 256, 0, stream>>>(cptr, adjc, h1b, NHIDD, dinv, agg1, NNODE);

  // ---- x1 = elu((agg1 + dinv^2*h1 + b1 + out1@gc1^T)*rnb) ----
  base(out1b, out1b, NFEATD, wgc1, wgc1, NFEATD, NFEATD, NFEATD, NHIDD, NHIDD, NHIDD);
  a.agg = agg1; a.hself = h1b; a.hld = NHIDD; a.dinv = dinv; a.bias = gc1b; a.rnb = rnb;
  a.elu = 1; a.outB = x1b;
  gemm_bt<3><<<dim3(2, MB), 256, 0, stream>>>(a);

  // ---- layer 2 neighbor mean ----
  spmm_nb2<<<NW4, 256, 0, stream>>>(rptr, adjr, x1b, nbscale, nb2p, NNODE);

  // ---- layer-2 relation GEMM ----
  base(x1b, nb2p, NHIDD, Wrel2, Wrel2 + 256, 512, NHIDD, 2 * NHIDD, NHIDD, NHIDD, 512);
  a.mrow = r2m; a.Xf = nullptr; a.Xh = x1b; a.nbm = nb2p; a.outG = out2g; a.outB2 = out2b;
  gemm_bt<2><<<dim3(4, MB), 256, 0, stream>>>(a);

  // ---- h2 = bf16(x1 @ gc2^T) ----
  base(x1b, x1b, NHIDD, wgc2, wgc2, NHIDD, NHIDD, NHIDD, NCLSD, NCLSD, NCLSD);
  a.outB = h2b;
  gemm_bt<0><<<dim3(1, MB), 256, 0, stream>>>(a);

  // ---- GCN aggregation layer 2 ----
  spmm_gcn64<<<NW4, 256, 0, stream>>>(cptr, adjc, h2b, NCLSD, dinv, agg2, NNODE);

  // ---- x2 + log_softmax fused: (agg2 + dinv^2*h2 + b2 + out2@gc2^T)*rnb ----
  base(out2b, out2b, NHIDD, wgc2, wgc2, NHIDD, NHIDD, NHIDD, NCLSD, NCLSD, NCLSD);
  a.agg = agg2; a.hself = h2b; a.hld = NCLSD; a.dinv = dinv; a.bias = gc2b; a.rnb = rnb;
  a.elu = 0; a.outF = out; a.outF2 = out + (size_t)NNODE * NCLSD;
  gemm_bt<4><<<dim3(1, MB), 256, 0, stream>>>(a);
}